// Round 6
// baseline (311.619 us; speedup 1.0000x reference)
//
#include <hip/hip_runtime.h>

typedef unsigned short u16;
typedef _Float16  f16x8  __attribute__((ext_vector_type(8)));
typedef _Float16  f16x4  __attribute__((ext_vector_type(4)));
typedef float     f32x4  __attribute__((ext_vector_type(4)));

#define MFMA_F16(a,b,c)  __builtin_amdgcn_mfma_f32_16x16x32_f16(a,b,c,0,0,0)

#define NTOK 64
#define DIM_ 128
#define SCALE_ 0.17677669529663687f   // 32^-0.5

__device__ __forceinline__ u16 f2h_u(float x) {
    _Float16 h = (_Float16)x;
    return __builtin_bit_cast(u16, h);
}

// ---------------- prep: repack f32 weights into fp16 MFMA B-fragment order ----------------
// ws: u16 frags [192 * 512]: [wq 0..31 | wkv 32..95 | wq_f 96..127 | wkv_f(k-half) 128..159 | wproj 160..191]
__global__ void wja_prep(const float* __restrict__ wq, const float* __restrict__ wkv,
                         const float* __restrict__ wq_f, const float* __restrict__ wkv_f,
                         const float* __restrict__ wproj, u16* __restrict__ ws)
{
    const int blk = blockIdx.x;
    const int l = threadIdx.x;          // 64 threads
    const float* W; int ldw, colbase;
    if (blk < 32)       { W = wq;    ldw = 128; colbase = (blk      >> 2) * 16; }
    else if (blk < 96)  { W = wkv;   ldw = 256; colbase = ((blk- 32) >> 2) * 16; }
    else if (blk < 128) { W = wq_f;  ldw = 128; colbase = ((blk- 96) >> 2) * 16; }
    else if (blk < 160) { W = wkv_f; ldw = 256; colbase = ((blk-128) >> 2) * 16; }
    else                { W = wproj; ldw = 128; colbase = ((blk-160) >> 2) * 16; }
    const int ks = blk & 3;
    const int m = l & 15, g = l >> 4;
    u16* dst = ws + blk * 512 + l * 8;
    #pragma unroll
    for (int i = 0; i < 8; ++i)
        dst[i] = f2h_u(W[(size_t)(32*ks + 8*g + i) * ldw + colbase + m]);
}

// ---------------- fused window joint attention ----------------
// 1 block = 1 window; 4 waves = 4 heads.
// LDS 54272 B (3 blocks/CU), u16 elems:
//   [0,18432): per-head 4608: qa[64][36] | ka[64][36]  (reused: qf/kf, then P[64][72] exact, then attn-out[64][40])
//   [18432,27136): per-head 2176: vT[32][68]
//   FIN f32 [64][132] overlays [0, 33792 B) in epilogue (after barrier)
// __launch_bounds__(256,3): 3 waves/SIMD -> ~170-VGPR budget; Sf is fused
// (never materialized) to fit. If spills appear -> WRITE_SIZE > 131072 KB.
__global__ __launch_bounds__(256, 3) void wja_fused(
    const float* __restrict__ x, const float* __restrict__ f,
    const float* __restrict__ bq, const float* __restrict__ bkv,
    const float* __restrict__ bq_f, const float* __restrict__ bkv_f,
    const float* __restrict__ bproj, const float* __restrict__ btab,
    const u16* __restrict__ ws, float* __restrict__ out)
{
    __shared__ __align__(16) u16 smem[27136];
    const int b    = blockIdx.x;
    const int tid  = threadIdx.x;
    const int h    = tid >> 6;
    const int lane = tid & 63;
    const int g    = lane >> 4;
    const int c    = lane & 15;
    const f32x4 zf4 = {0.f, 0.f, 0.f, 0.f};

    u16* const qa = smem + h * 4608;          // also P (stride 72) and attn-out (stride 40)
    u16* const ka = qa + 2304;
    u16* const va = smem + 18432 + h * 2176;  // vT[32][68]

    const float* const xb = x + (size_t)b * (NTOK * DIM_);
    const float* const fb = f + (size_t)b * (NTOK * DIM_);

    auto ldf16 = [](const float* p) -> f16x8 {
        f16x8 r;
        #pragma unroll
        for (int i = 0; i < 8; ++i) r[i] = (_Float16)p[i];
        return r;
    };
    // LDS read of 8 fp16 at 8-B (not 16-B) alignment: two b64 loads
    auto ldlds8 = [](const u16* p) -> f16x8 {
        struct P2 { f16x4 lo, hi; } t;
        t.lo = *(const f16x4*)p;
        t.hi = *(const f16x4*)(p + 4);
        return __builtin_bit_cast(f16x8, t);
    };

    // stage-A GEMM: A-frags (regs) x ws-frags -> 32 cols for this head -> LDS fp16
    auto gemmA = [&](const f16x8* afr, int fragbase, const float* biasv,
                     u16* dst, int dstride, bool transposed) {
        #pragma unroll
        for (int lct = 0; lct < 2; ++lct) {
            f32x4 acc[4] = { zf4, zf4, zf4, zf4 };
            #pragma unroll
            for (int ks = 0; ks < 4; ++ks) {
                f16x8 bfr = *(const f16x8*)(ws + (fragbase + lct*4 + ks) * 512 + lane * 8);
                #pragma unroll
                for (int mt = 0; mt < 4; ++mt)
                    acc[mt] = MFMA_F16(afr[mt*4+ks], bfr, acc[mt]);
            }
            float bv = biasv[lct*16 + c];
            #pragma unroll
            for (int mt = 0; mt < 4; ++mt)
                #pragma unroll
                for (int i = 0; i < 4; ++i) {
                    int row = 16*mt + 4*g + i;
                    int col = 16*lct + c;
                    u16 v = f2h_u(acc[mt][i] + bv);
                    if (transposed) dst[col * dstride + row] = v;
                    else            dst[row * dstride + col] = v;
                }
        }
    };

    // ---- x A-frags (f32 -> fp16), then q,k,v ----
    f16x8 xfr[16];
    #pragma unroll
    for (int mt = 0; mt < 4; ++mt)
        #pragma unroll
        for (int ks = 0; ks < 4; ++ks)
            xfr[mt*4+ks] = ldf16(xb + (16*mt + c) * DIM_ + 32*ks + 8*g);

    gemmA(xfr,   0 + 8*h, bq        + 32*h, qa, 36, false);   // q
    gemmA(xfr,  32 + 8*h, bkv       + 32*h, ka, 36, false);   // k
    gemmA(xfr,  64 + 8*h, bkv + 128 + 32*h, va, 68, true);    // v -> vT[32][68]

    // ---- S = q k^T ----
    f32x4 S[4][4];
    {
        f16x8 qfr[4], kfr[4];
        #pragma unroll
        for (int t = 0; t < 4; ++t) {
            qfr[t] = ldlds8(qa + (16*t + c) * 36 + 8*g);
            kfr[t] = ldlds8(ka + (16*t + c) * 36 + 8*g);
        }
        #pragma unroll
        for (int mt = 0; mt < 4; ++mt)
            #pragma unroll
            for (int nt = 0; nt < 4; ++nt)
                S[mt][nt] = MFMA_F16(qfr[mt], kfr[nt], zf4);
    }

    // ---- f A-frags, then qf,kf overwrite qa/ka (same-wave DS ordering is safe) ----
    {
        f16x8 ffr[16];
        #pragma unroll
        for (int mt = 0; mt < 4; ++mt)
            #pragma unroll
            for (int ks = 0; ks < 4; ++ks)
                ffr[mt*4+ks] = ldf16(fb + (16*mt + c) * DIM_ + 32*ks + 8*g);

        gemmA(ffr,  96 + 8*h, bq_f  + 32*h, qa, 36, false);   // q_f
        gemmA(ffr, 128 + 8*h, bkv_f + 32*h, ka, 36, false);   // k_f
    }

    // ---- Sf fused with joint modulation: S = (S*scale+b) * (sf*scale+b) ----
    // sf computed one 16x16 tile at a time -> never materialized (reg budget).
    {
        f16x8 qfr[4], kfr[4];
        #pragma unroll
        for (int t = 0; t < 4; ++t) {
            qfr[t] = ldlds8(qa + (16*t + c) * 36 + 8*g);
            kfr[t] = ldlds8(ka + (16*t + c) * 36 + 8*g);
        }
        #pragma unroll
        for (int mt = 0; mt < 4; ++mt)
            #pragma unroll
            for (int nt = 0; nt < 4; ++nt) {
                f32x4 sf = MFMA_F16(qfr[mt], kfr[nt], zf4);
                int j = 16*nt + c;
                #pragma unroll
                for (int i = 0; i < 4; ++i) {
                    int r = 16*mt + 4*g + i;
                    int idx = ((r >> 3) - (j >> 3) + 7) * 15 + ((r & 7) - (j & 7) + 7);
                    float bv = btab[idx * 4 + h];
                    S[mt][nt][i] = (S[mt][nt][i] * SCALE_ + bv) * (sf[i] * SCALE_ + bv);
                }
            }
    }

    // ---- softmax over rows ----
    float rmax[4][4], rinv[4][4];
    #pragma unroll
    for (int mt = 0; mt < 4; ++mt)
        #pragma unroll
        for (int i = 0; i < 4; ++i) {
            float m = fmaxf(fmaxf(S[mt][0][i], S[mt][1][i]), fmaxf(S[mt][2][i], S[mt][3][i]));
            #pragma unroll
            for (int d = 1; d < 16; d <<= 1) m = fmaxf(m, __shfl_xor(m, d));
            rmax[mt][i] = m;
        }
    #pragma unroll
    for (int mt = 0; mt < 4; ++mt)
        #pragma unroll
        for (int i = 0; i < 4; ++i) {
            float s0 = 0.f;
            #pragma unroll
            for (int nt = 0; nt < 4; ++nt) {
                float e = __expf(S[mt][nt][i] - rmax[mt][i]);
                S[mt][nt][i] = e;
                s0 += e;
            }
            #pragma unroll
            for (int d = 1; d < 16; d <<= 1) s0 += __shfl_xor(s0, d);
            rinv[mt][i] = 1.0f / s0;
        }

    // ---- P (fp16) -> per-head block, stride 72 (64x72 = 4608 exact fit) ----
    #pragma unroll
    for (int mt = 0; mt < 4; ++mt)
        #pragma unroll
        for (int nt = 0; nt < 4; ++nt)
            #pragma unroll
            for (int i = 0; i < 4; ++i)
                qa[(16*mt + 4*g + i) * 72 + 16*nt + c] = f2h_u(S[mt][nt][i] * rinv[mt][i]);

    // ---- O = P @ v (K=64 via vT) ----
    f32x4 O[4][2] = { { zf4, zf4 }, { zf4, zf4 }, { zf4, zf4 }, { zf4, zf4 } };
    #pragma unroll
    for (int ks = 0; ks < 2; ++ks) {
        f16x8 pfr[4], vfr[2];
        #pragma unroll
        for (int mt = 0; mt < 4; ++mt)
            pfr[mt] = *(const f16x8*)(qa + (16*mt + c) * 72 + 32*ks + 8*g);   // 144-B rows: aligned
        #pragma unroll
        for (int nt = 0; nt < 2; ++nt)
            vfr[nt] = ldlds8(va + (16*nt + c) * 68 + 32*ks + 8*g);
        #pragma unroll
        for (int mt = 0; mt < 4; ++mt)
            #pragma unroll
            for (int nt = 0; nt < 2; ++nt)
                O[mt][nt] = MFMA_F16(pfr[mt], vfr[nt], O[mt][nt]);
    }

    // attn-out (fp16) -> per-head block as [64][40] (overwrites P; same-wave order OK)
    #pragma unroll
    for (int mt = 0; mt < 4; ++mt)
        #pragma unroll
        for (int nt = 0; nt < 2; ++nt)
            #pragma unroll
            for (int i = 0; i < 4; ++i)
                qa[(16*mt + 4*g + i) * 40 + 16*nt + c] = f2h_u(O[mt][nt][i]);

    __syncthreads();

    // ---- proj: wave h computes cols [32h, 32h+32) over all K=128 (4 source heads) ----
    f32x4 PO[4][2] = { { zf4, zf4 }, { zf4, zf4 }, { zf4, zf4 }, { zf4, zf4 } };
    #pragma unroll
    for (int ks = 0; ks < 4; ++ks) {
        const u16* ao = smem + ks * 4608;
        f16x8 afr[4];
        #pragma unroll
        for (int mt = 0; mt < 4; ++mt)
            afr[mt] = *(const f16x8*)(ao + (16*mt + c) * 40 + 8*g);          // 80-B rows: aligned
        #pragma unroll
        for (int lct = 0; lct < 2; ++lct) {
            f16x8 bfr = *(const f16x8*)(ws + (160 + (2*h + lct) * 4 + ks) * 512 + lane * 8);
            #pragma unroll
            for (int mt = 0; mt < 4; ++mt)
                PO[mt][lct] = MFMA_F16(afr[mt], bfr, PO[mt][lct]);
        }
    }
    __syncthreads();   // FIN overlaps attn-out regions other waves may still be reading

    // FIN f32 [64][132] overlays smem bytes [0, 33792)
    float* const fin = (float*)smem;
    #pragma unroll
    for (int lct = 0; lct < 2; ++lct) {
        float bv = bproj[32*h + 16*lct + c];
        #pragma unroll
        for (int mt = 0; mt < 4; ++mt)
            #pragma unroll
            for (int i = 0; i < 4; ++i)
                fin[(16*mt + 4*g + i) * 132 + 32*h + 16*lct + c] = PO[mt][lct][i] + bv;
    }
    __syncthreads();

    // ---- coalesced f32 store: 64 rows x 128 cols ----
    {
        const int row = tid >> 2, cb = (tid & 3) * 32;
        float* gout = out + (size_t)b * 8192 + row * 128 + cb;
        const float* src = fin + row * 132 + cb;
        #pragma unroll
        for (int q2 = 0; q2 < 8; ++q2)
            *(f32x4*)(gout + q2 * 4) = *(const f32x4*)(src + q2 * 4);
    }
}

extern "C" void kernel_launch(void* const* d_in, const int* in_sizes, int n_in,
                              void* d_out, int out_size, void* d_ws, size_t ws_size,
                              hipStream_t stream)
{
    const float* x     = (const float*)d_in[0];
    const float* f     = (const float*)d_in[1];
    const float* wq    = (const float*)d_in[2];
    const float* bq    = (const float*)d_in[3];
    const float* wkv   = (const float*)d_in[4];
    const float* bkv   = (const float*)d_in[5];
    const float* wq_f  = (const float*)d_in[6];
    const float* bq_f  = (const float*)d_in[7];
    const float* wkv_f = (const float*)d_in[8];
    const float* bkv_f = (const float*)d_in[9];
    const float* btab  = (const float*)d_in[10];
    const float* wproj = (const float*)d_in[11];
    const float* bproj = (const float*)d_in[12];
    u16* ws    = (u16*)d_ws;
    float* out = (float*)d_out;

    hipLaunchKernelGGL(wja_prep, dim3(192), dim3(64), 0, stream,
                       wq, wkv, wq_f, wkv_f, wproj, ws);
    hipLaunchKernelGGL(wja_fused, dim3(4096), dim3(256), 0, stream,
                       x, f, bq, bkv, bq_f, bkv_f, bproj, btab, ws, out);
}

// Round 7
// 229.165 us; speedup vs baseline: 1.3598x; 1.3598x over previous
//
#include <hip/hip_runtime.h>

typedef unsigned short u16;
typedef _Float16  f16x8  __attribute__((ext_vector_type(8)));
typedef _Float16  f16x4  __attribute__((ext_vector_type(4)));
typedef float     f32x4  __attribute__((ext_vector_type(4)));

#define MFMA_F16(a,b,c)  __builtin_amdgcn_mfma_f32_16x16x32_f16(a,b,c,0,0,0)

#define NTOK 64
#define DIM_ 128
#define SCALE_ 0.17677669529663687f   // 32^-0.5

__device__ __forceinline__ u16 f2h_u(float x) {
    _Float16 h = (_Float16)x;
    return __builtin_bit_cast(u16, h);
}

// ---------------- prep: repack f32 weights into fp16 MFMA B-fragment order ----------------
// ws: u16 frags [192 * 512]: [wq 0..31 | wkv 32..95 | wq_f 96..127 | wkv_f(k-half) 128..159 | wproj 160..191]
__global__ void wja_prep(const float* __restrict__ wq, const float* __restrict__ wkv,
                         const float* __restrict__ wq_f, const float* __restrict__ wkv_f,
                         const float* __restrict__ wproj, u16* __restrict__ ws)
{
    const int blk = blockIdx.x;
    const int l = threadIdx.x;          // 64 threads
    const float* W; int ldw, colbase;
    if (blk < 32)       { W = wq;    ldw = 128; colbase = (blk      >> 2) * 16; }
    else if (blk < 96)  { W = wkv;   ldw = 256; colbase = ((blk- 32) >> 2) * 16; }
    else if (blk < 128) { W = wq_f;  ldw = 128; colbase = ((blk- 96) >> 2) * 16; }
    else if (blk < 160) { W = wkv_f; ldw = 256; colbase = ((blk-128) >> 2) * 16; }
    else                { W = wproj; ldw = 128; colbase = ((blk-160) >> 2) * 16; }
    const int ks = blk & 3;
    const int m = l & 15, g = l >> 4;
    u16* dst = ws + blk * 512 + l * 8;
    #pragma unroll
    for (int i = 0; i < 8; ++i)
        dst[i] = f2h_u(W[(size_t)(32*ks + 8*g + i) * ldw + colbase + m]);
}

// ---------------- fused window joint attention ----------------
// 1 block = 1 window; 4 waves. Stage-A: wave w = 16-token slice (all heads).
// Attention phases: wave w = head w.
// LDS 54272 B (3 blocks/CU), u16 elems:
//   [0,18432): per-head 4608: qa[64][36] | ka[64][36]  (reused: qf/kf, then P[64][72], then attn-out[64][40])
//   [18432,27136): per-head 2176: vT[32][68]
//   FIN f32 [64][132] overlays [0, 33792 B) in epilogue
// waves_per_eu(3,3): pin budget to 512/3~170 VGPRs — R6 showed launch_bounds(,3)
// lets the heuristic target 6 waves/EU (VGPR=84) and spill ~250 MB.
__global__ __launch_bounds__(256) __attribute__((amdgpu_waves_per_eu(3, 3)))
void wja_fused(
    const float* __restrict__ x, const float* __restrict__ f,
    const float* __restrict__ bq, const float* __restrict__ bkv,
    const float* __restrict__ bq_f, const float* __restrict__ bkv_f,
    const float* __restrict__ bproj, const float* __restrict__ btab,
    const u16* __restrict__ ws, float* __restrict__ out)
{
    __shared__ __align__(16) u16 smem[27136];
    const int b    = blockIdx.x;
    const int tid  = threadIdx.x;
    const int w    = tid >> 6;        // stage-A: token-slice id; attention: head id
    const int lane = tid & 63;
    const int g    = lane >> 4;
    const int c    = lane & 15;
    const f32x4 zf4 = {0.f, 0.f, 0.f, 0.f};

    u16* const hq = smem + w * 4608;          // this head's q / qf / P / attn-out
    u16* const hk = hq + 2304;                // this head's k / kf
    u16* const hv = smem + 18432 + w * 2176;  // this head's vT[32][68]

    const float* const xb = x + (size_t)b * (NTOK * DIM_);
    const float* const fb = f + (size_t)b * (NTOK * DIM_);

    auto ldf16 = [](const float* p) -> f16x8 {
        f16x8 r;
        #pragma unroll
        for (int i = 0; i < 8; ++i) r[i] = (_Float16)p[i];
        return r;
    };
    // LDS read of 8 fp16 at 8-B (not 16-B) alignment: two b64 loads
    auto ldlds8 = [](const u16* p) -> f16x8 {
        struct P2 { f16x4 lo, hi; } t;
        t.lo = *(const f16x4*)p;
        t.hi = *(const f16x4*)(p + 4);
        return __builtin_bit_cast(f16x8, t);
    };

    // stage-A GEMM, token-sliced: this wave's 16 token rows x all 128 out-cols.
    // which: 0 -> q-area [64][36]; 1 -> k-area [64][36]; 2 -> vT [32][68] transposed
    auto gemmA = [&](const f16x8* afr, int wbase, const float* biasv, int which) {
        #pragma unroll
        for (int lct = 0; lct < 8; ++lct) {
            f32x4 acc = zf4;
            #pragma unroll
            for (int ks = 0; ks < 4; ++ks) {
                f16x8 bfr = *(const f16x8*)(ws + (wbase + 4*lct + ks) * 512 + lane * 8);
                acc = MFMA_F16(afr[ks], bfr, acc);
            }
            float bv = biasv[16*lct + c];
            const int hh = lct >> 1;
            const int cc = ((lct & 1) << 4) + c;
            #pragma unroll
            for (int i = 0; i < 4; ++i) {
                int row = 16*w + 4*g + i;
                u16 vv = f2h_u(acc[i] + bv);
                if (which == 0)      smem[hh*4608 + row*36 + cc] = vv;
                else if (which == 1) smem[hh*4608 + 2304 + row*36 + cc] = vv;
                else                 smem[18432 + hh*2176 + cc*68 + row] = vv;
            }
        }
    };

    // ---- stage qkv (x path): 4 A-frags only ----
    {
        f16x8 xfr[4];
        #pragma unroll
        for (int ks = 0; ks < 4; ++ks)
            xfr[ks] = ldf16(xb + (16*w + c) * DIM_ + 32*ks + 8*g);
        gemmA(xfr,   0, bq,        0);   // q
        gemmA(xfr,  32, bkv,       1);   // k
        gemmA(xfr,  64, bkv + 128, 2);   // v -> vT
    }
    __syncthreads();

    // ---- S = q k^T (head = w) ----
    f32x4 S[4][4];
    {
        f16x8 qfr[4], kfr[4];
        #pragma unroll
        for (int t = 0; t < 4; ++t) {
            qfr[t] = ldlds8(hq + (16*t + c) * 36 + 8*g);
            kfr[t] = ldlds8(hk + (16*t + c) * 36 + 8*g);
        }
        #pragma unroll
        for (int mt = 0; mt < 4; ++mt)
            #pragma unroll
            for (int nt = 0; nt < 4; ++nt)
                S[mt][nt] = MFMA_F16(qfr[mt], kfr[nt], zf4);
    }
    __syncthreads();   // all S-frag LDS reads done before qf/kf overwrite

    // ---- stage qf,kf (f path) ----
    {
        f16x8 ffr[4];
        #pragma unroll
        for (int ks = 0; ks < 4; ++ks)
            ffr[ks] = ldf16(fb + (16*w + c) * DIM_ + 32*ks + 8*g);
        gemmA(ffr,  96, bq_f,  0);   // q_f
        gemmA(ffr, 128, bkv_f, 1);   // k_f
    }
    __syncthreads();

    // ---- Sf fused with joint modulation: S = (S*scale+b) * (sf*scale+b) ----
    {
        f16x8 qfr[4], kfr[4];
        #pragma unroll
        for (int t = 0; t < 4; ++t) {
            qfr[t] = ldlds8(hq + (16*t + c) * 36 + 8*g);
            kfr[t] = ldlds8(hk + (16*t + c) * 36 + 8*g);
        }
        #pragma unroll
        for (int mt = 0; mt < 4; ++mt)
            #pragma unroll
            for (int nt = 0; nt < 4; ++nt) {
                f32x4 sf = MFMA_F16(qfr[mt], kfr[nt], zf4);
                int j = 16*nt + c;
                #pragma unroll
                for (int i = 0; i < 4; ++i) {
                    int r = 16*mt + 4*g + i;
                    int idx = ((r >> 3) - (j >> 3) + 7) * 15 + ((r & 7) - (j & 7) + 7);
                    float bv = btab[idx * 4 + w];
                    S[mt][nt][i] = (S[mt][nt][i] * SCALE_ + bv) * (sf[i] * SCALE_ + bv);
                }
            }
    }

    // ---- softmax over rows ----
    float rmax[4][4], rinv[4][4];
    #pragma unroll
    for (int mt = 0; mt < 4; ++mt)
        #pragma unroll
        for (int i = 0; i < 4; ++i) {
            float m = fmaxf(fmaxf(S[mt][0][i], S[mt][1][i]), fmaxf(S[mt][2][i], S[mt][3][i]));
            #pragma unroll
            for (int d = 1; d < 16; d <<= 1) m = fmaxf(m, __shfl_xor(m, d));
            rmax[mt][i] = m;
        }
    #pragma unroll
    for (int mt = 0; mt < 4; ++mt)
        #pragma unroll
        for (int i = 0; i < 4; ++i) {
            float s0 = 0.f;
            #pragma unroll
            for (int nt = 0; nt < 4; ++nt) {
                float e = __expf(S[mt][nt][i] - rmax[mt][i]);
                S[mt][nt][i] = e;
                s0 += e;
            }
            #pragma unroll
            for (int d = 1; d < 16; d <<= 1) s0 += __shfl_xor(s0, d);
            rinv[mt][i] = 1.0f / s0;
        }

    // ---- P (fp16) -> own head block, stride 72 (64x72 = 4608 exact fit) ----
    // Only wave w touches head-w's region after the staging barrier above.
    #pragma unroll
    for (int mt = 0; mt < 4; ++mt)
        #pragma unroll
        for (int nt = 0; nt < 4; ++nt)
            #pragma unroll
            for (int i = 0; i < 4; ++i)
                hq[(16*mt + 4*g + i) * 72 + 16*nt + c] = f2h_u(S[mt][nt][i] * rinv[mt][i]);

    // ---- O = P @ v (K=64 via vT) ----
    f32x4 O[4][2] = { { zf4, zf4 }, { zf4, zf4 }, { zf4, zf4 }, { zf4, zf4 } };
    #pragma unroll
    for (int ks = 0; ks < 2; ++ks) {
        f16x8 pfr[4], vfr[2];
        #pragma unroll
        for (int mt = 0; mt < 4; ++mt)
            pfr[mt] = *(const f16x8*)(hq + (16*mt + c) * 72 + 32*ks + 8*g);   // 144-B rows: aligned
        #pragma unroll
        for (int nt = 0; nt < 2; ++nt)
            vfr[nt] = ldlds8(hv + (16*nt + c) * 68 + 32*ks + 8*g);
        #pragma unroll
        for (int mt = 0; mt < 4; ++mt)
            #pragma unroll
            for (int nt = 0; nt < 2; ++nt)
                O[mt][nt] = MFMA_F16(pfr[mt], vfr[nt], O[mt][nt]);
    }

    // attn-out (fp16) -> own head block as [64][40] (overwrites P; same-wave order OK)
    #pragma unroll
    for (int mt = 0; mt < 4; ++mt)
        #pragma unroll
        for (int nt = 0; nt < 2; ++nt)
            #pragma unroll
            for (int i = 0; i < 4; ++i)
                hq[(16*mt + 4*g + i) * 40 + 16*nt + c] = f2h_u(O[mt][nt][i]);

    __syncthreads();

    // ---- proj: wave w computes cols [32w, 32w+32) over all K=128 (4 source heads) ----
    f32x4 PO[4][2] = { { zf4, zf4 }, { zf4, zf4 }, { zf4, zf4 }, { zf4, zf4 } };
    #pragma unroll
    for (int ks = 0; ks < 4; ++ks) {
        const u16* ao = smem + ks * 4608;
        f16x8 afr[4];
        #pragma unroll
        for (int mt = 0; mt < 4; ++mt)
            afr[mt] = *(const f16x8*)(ao + (16*mt + c) * 40 + 8*g);          // 80-B rows: aligned
        #pragma unroll
        for (int lct = 0; lct < 2; ++lct) {
            f16x8 bfr = *(const f16x8*)(ws + (160 + (2*w + lct) * 4 + ks) * 512 + lane * 8);
            #pragma unroll
            for (int mt = 0; mt < 4; ++mt)
                PO[mt][lct] = MFMA_F16(afr[mt], bfr, PO[mt][lct]);
        }
    }
    __syncthreads();   // FIN overlaps attn-out regions other waves may still be reading

    // FIN f32 [64][132] overlays smem bytes [0, 33792)
    float* const fin = (float*)smem;
    #pragma unroll
    for (int lct = 0; lct < 2; ++lct) {
        float bv = bproj[32*w + 16*lct + c];
        #pragma unroll
        for (int mt = 0; mt < 4; ++mt)
            #pragma unroll
            for (int i = 0; i < 4; ++i)
                fin[(16*mt + 4*g + i) * 132 + 32*w + 16*lct + c] = PO[mt][lct][i] + bv;
    }
    __syncthreads();

    // ---- coalesced f32 store: 64 rows x 128 cols ----
    {
        const int row = tid >> 2, cb = (tid & 3) * 32;
        float* gout = out + (size_t)b * 8192 + row * 128 + cb;
        const float* src = fin + row * 132 + cb;
        #pragma unroll
        for (int q2 = 0; q2 < 8; ++q2)
            *(f32x4*)(gout + q2 * 4) = *(const f32x4*)(src + q2 * 4);
    }
}

extern "C" void kernel_launch(void* const* d_in, const int* in_sizes, int n_in,
                              void* d_out, int out_size, void* d_ws, size_t ws_size,
                              hipStream_t stream)
{
    const float* x     = (const float*)d_in[0];
    const float* f     = (const float*)d_in[1];
    const float* wq    = (const float*)d_in[2];
    const float* bq    = (const float*)d_in[3];
    const float* wkv   = (const float*)d_in[4];
    const float* bkv   = (const float*)d_in[5];
    const float* wq_f  = (const float*)d_in[6];
    const float* bq_f  = (const float*)d_in[7];
    const float* wkv_f = (const float*)d_in[8];
    const float* bkv_f = (const float*)d_in[9];
    const float* btab  = (const float*)d_in[10];
    const float* wproj = (const float*)d_in[11];
    const float* bproj = (const float*)d_in[12];
    u16* ws    = (u16*)d_ws;
    float* out = (float*)d_out;

    hipLaunchKernelGGL(wja_prep, dim3(192), dim3(64), 0, stream,
                       wq, wkv, wq_f, wkv_f, wproj, ws);
    hipLaunchKernelGGL(wja_fused, dim3(4096), dim3(256), 0, stream,
                       x, f, bq, bkv, bq_f, bkv_f, bproj, btab, ws, out);
}

// Round 8
// 217.098 us; speedup vs baseline: 1.4354x; 1.0556x over previous
//
#include <hip/hip_runtime.h>

typedef unsigned short u16;
typedef _Float16  f16x8  __attribute__((ext_vector_type(8)));
typedef _Float16  f16x4  __attribute__((ext_vector_type(4)));
typedef float     f32x4  __attribute__((ext_vector_type(4)));

#define MFMA_F16(a,b,c)  __builtin_amdgcn_mfma_f32_16x16x32_f16(a,b,c,0,0,0)

#define NTOK 64
#define DIM_ 128
#define SCALE_ 0.17677669529663687f   // 32^-0.5

__device__ __forceinline__ u16 f2h_u(float x) {
    _Float16 h = (_Float16)x;
    return __builtin_bit_cast(u16, h);
}

// ---------------- prep: repack f32 weights into fp16 MFMA B-fragment order ----------------
// ws: u16 frags [192 * 512]: [wq 0..31 | wkv 32..95 | wq_f 96..127 | wkv_f(k-half) 128..159 | wproj 160..191]
__global__ void wja_prep(const float* __restrict__ wq, const float* __restrict__ wkv,
                         const float* __restrict__ wq_f, const float* __restrict__ wkv_f,
                         const float* __restrict__ wproj, u16* __restrict__ ws)
{
    const int blk = blockIdx.x;
    const int l = threadIdx.x;          // 64 threads
    const float* W; int ldw, colbase;
    if (blk < 32)       { W = wq;    ldw = 128; colbase = (blk      >> 2) * 16; }
    else if (blk < 96)  { W = wkv;   ldw = 256; colbase = ((blk- 32) >> 2) * 16; }
    else if (blk < 128) { W = wq_f;  ldw = 128; colbase = ((blk- 96) >> 2) * 16; }
    else if (blk < 160) { W = wkv_f; ldw = 256; colbase = ((blk-128) >> 2) * 16; }
    else                { W = wproj; ldw = 128; colbase = ((blk-160) >> 2) * 16; }
    const int ks = blk & 3;
    const int m = l & 15, g = l >> 4;
    u16* dst = ws + blk * 512 + l * 8;
    #pragma unroll
    for (int i = 0; i < 8; ++i)
        dst[i] = f2h_u(W[(size_t)(32*ks + 8*g + i) * ldw + colbase + m]);
}

// ---------------- fused window joint attention ----------------
// 1 block = 1 window; 4 waves. Stage-A: wave w = 16-token slice (all heads).
// Attention phases: wave w = head w.
// LDS 54272 B (3 blocks/CU), u16 elems:
//   [0,18432): per-head 4608: qa[64][36] | ka[64][36]  (reused: qf/kf, then P[64][72], then attn-out[64][40])
//   [18432,27136): per-head 2176: vT[32][68]
//   FIN f32 [64][132] overlays [0, 33792 B) in epilogue
// __launch_bounds__(256,2): empirically (R5) the only setting that avoids
// spills — VGPR=112, under the 170 needed for 3 blocks/CU (LDS-capped).
// (,3) and waves_per_eu(3,3) both made the allocator pick 84 and spill (R6/R7).
__global__ __launch_bounds__(256, 2)
void wja_fused(
    const float* __restrict__ x, const float* __restrict__ f,
    const float* __restrict__ bq, const float* __restrict__ bkv,
    const float* __restrict__ bq_f, const float* __restrict__ bkv_f,
    const float* __restrict__ bproj, const float* __restrict__ btab,
    const u16* __restrict__ ws, float* __restrict__ out)
{
    __shared__ __align__(16) u16 smem[27136];
    const int b    = blockIdx.x;
    const int tid  = threadIdx.x;
    const int w    = tid >> 6;        // stage-A: token-slice id; attention: head id
    const int lane = tid & 63;
    const int g    = lane >> 4;
    const int c    = lane & 15;
    const f32x4 zf4 = {0.f, 0.f, 0.f, 0.f};

    u16* const hq = smem + w * 4608;          // this head's q / qf / P / attn-out
    u16* const hk = hq + 2304;                // this head's k / kf
    u16* const hv = smem + 18432 + w * 2176;  // this head's vT[32][68]

    const float* const xb = x + (size_t)b * (NTOK * DIM_);
    const float* const fb = f + (size_t)b * (NTOK * DIM_);

    auto ldf16 = [](const float* p) -> f16x8 {
        f16x8 r;
        #pragma unroll
        for (int i = 0; i < 8; ++i) r[i] = (_Float16)p[i];
        return r;
    };
    // LDS read of 8 fp16 at 8-B (not 16-B) alignment: two b64 loads
    auto ldlds8 = [](const u16* p) -> f16x8 {
        struct P2 { f16x4 lo, hi; } t;
        t.lo = *(const f16x4*)p;
        t.hi = *(const f16x4*)(p + 4);
        return __builtin_bit_cast(f16x8, t);
    };

    // stage-A GEMM, token-sliced: this wave's 16 token rows x all 128 out-cols.
    // which: 0 -> q-area [64][36]; 1 -> k-area [64][36]; 2 -> vT [32][68] transposed
    auto gemmA = [&](const f16x8* afr, int wbase, const float* biasv, int which) {
        #pragma unroll
        for (int lct = 0; lct < 8; ++lct) {
            f32x4 acc = zf4;
            #pragma unroll
            for (int ks = 0; ks < 4; ++ks) {
                f16x8 bfr = *(const f16x8*)(ws + (wbase + 4*lct + ks) * 512 + lane * 8);
                acc = MFMA_F16(afr[ks], bfr, acc);
            }
            float bv = biasv[16*lct + c];
            const int hh = lct >> 1;
            const int cc = ((lct & 1) << 4) + c;
            #pragma unroll
            for (int i = 0; i < 4; ++i) {
                int row = 16*w + 4*g + i;
                u16 vv = f2h_u(acc[i] + bv);
                if (which == 0)      smem[hh*4608 + row*36 + cc] = vv;
                else if (which == 1) smem[hh*4608 + 2304 + row*36 + cc] = vv;
                else                 smem[18432 + hh*2176 + cc*68 + row] = vv;
            }
        }
    };

    // ---- stage qkv (x path): 4 A-frags only ----
    {
        f16x8 xfr[4];
        #pragma unroll
        for (int ks = 0; ks < 4; ++ks)
            xfr[ks] = ldf16(xb + (16*w + c) * DIM_ + 32*ks + 8*g);
        gemmA(xfr,   0, bq,        0);   // q
        gemmA(xfr,  32, bkv,       1);   // k
        gemmA(xfr,  64, bkv + 128, 2);   // v -> vT
    }
    __syncthreads();

    // ---- S = q k^T (head = w) ----
    f32x4 S[4][4];
    {
        f16x8 qfr[4], kfr[4];
        #pragma unroll
        for (int t = 0; t < 4; ++t) {
            qfr[t] = ldlds8(hq + (16*t + c) * 36 + 8*g);
            kfr[t] = ldlds8(hk + (16*t + c) * 36 + 8*g);
        }
        #pragma unroll
        for (int mt = 0; mt < 4; ++mt)
            #pragma unroll
            for (int nt = 0; nt < 4; ++nt)
                S[mt][nt] = MFMA_F16(qfr[mt], kfr[nt], zf4);
    }
    __syncthreads();   // all S-frag LDS reads done before qf/kf overwrite

    // ---- stage qf,kf (f path) ----
    {
        f16x8 ffr[4];
        #pragma unroll
        for (int ks = 0; ks < 4; ++ks)
            ffr[ks] = ldf16(fb + (16*w + c) * DIM_ + 32*ks + 8*g);
        gemmA(ffr,  96, bq_f,  0);   // q_f
        gemmA(ffr, 128, bkv_f, 1);   // k_f
    }
    __syncthreads();

    // ---- Sf fused with joint modulation: S = (S*scale+b) * (sf*scale+b) ----
    // kfr loaded once; qfr loaded per-mt (smaller peak live set).
    {
        f16x8 kfr[4];
        #pragma unroll
        for (int t = 0; t < 4; ++t)
            kfr[t] = ldlds8(hk + (16*t + c) * 36 + 8*g);
        #pragma unroll
        for (int mt = 0; mt < 4; ++mt) {
            f16x8 qfr = ldlds8(hq + (16*mt + c) * 36 + 8*g);
            #pragma unroll
            for (int nt = 0; nt < 4; ++nt) {
                f32x4 sf = MFMA_F16(qfr, kfr[nt], zf4);
                int j = 16*nt + c;
                #pragma unroll
                for (int i = 0; i < 4; ++i) {
                    int r = 16*mt + 4*g + i;
                    int idx = ((r >> 3) - (j >> 3) + 7) * 15 + ((r & 7) - (j & 7) + 7);
                    float bv = btab[idx * 4 + w];
                    S[mt][nt][i] = (S[mt][nt][i] * SCALE_ + bv) * (sf[i] * SCALE_ + bv);
                }
            }
        }
    }

    // ---- softmax over rows ----
    float rmax[4][4], rinv[4][4];
    #pragma unroll
    for (int mt = 0; mt < 4; ++mt)
        #pragma unroll
        for (int i = 0; i < 4; ++i) {
            float m = fmaxf(fmaxf(S[mt][0][i], S[mt][1][i]), fmaxf(S[mt][2][i], S[mt][3][i]));
            #pragma unroll
            for (int d = 1; d < 16; d <<= 1) m = fmaxf(m, __shfl_xor(m, d));
            rmax[mt][i] = m;
        }
    #pragma unroll
    for (int mt = 0; mt < 4; ++mt)
        #pragma unroll
        for (int i = 0; i < 4; ++i) {
            float s0 = 0.f;
            #pragma unroll
            for (int nt = 0; nt < 4; ++nt) {
                float e = __expf(S[mt][nt][i] - rmax[mt][i]);
                S[mt][nt][i] = e;
                s0 += e;
            }
            #pragma unroll
            for (int d = 1; d < 16; d <<= 1) s0 += __shfl_xor(s0, d);
            rinv[mt][i] = 1.0f / s0;
        }

    // ---- P (fp16) -> own head block, stride 72 (64x72 = 4608 exact fit) ----
    // Only wave w touches head-w's region after the staging barrier above.
    #pragma unroll
    for (int mt = 0; mt < 4; ++mt)
        #pragma unroll
        for (int nt = 0; nt < 4; ++nt)
            #pragma unroll
            for (int i = 0; i < 4; ++i)
                hq[(16*mt + 4*g + i) * 72 + 16*nt + c] = f2h_u(S[mt][nt][i] * rinv[mt][i]);

    // ---- O = P @ v (K=64 via vT) ----
    f32x4 O[4][2] = { { zf4, zf4 }, { zf4, zf4 }, { zf4, zf4 }, { zf4, zf4 } };
    #pragma unroll
    for (int ks = 0; ks < 2; ++ks) {
        f16x8 pfr[4], vfr[2];
        #pragma unroll
        for (int mt = 0; mt < 4; ++mt)
            pfr[mt] = *(const f16x8*)(hq + (16*mt + c) * 72 + 32*ks + 8*g);   // 144-B rows: aligned
        #pragma unroll
        for (int nt = 0; nt < 2; ++nt)
            vfr[nt] = ldlds8(hv + (16*nt + c) * 68 + 32*ks + 8*g);
        #pragma unroll
        for (int mt = 0; mt < 4; ++mt)
            #pragma unroll
            for (int nt = 0; nt < 2; ++nt)
                O[mt][nt] = MFMA_F16(pfr[mt], vfr[nt], O[mt][nt]);
    }

    // attn-out (fp16) -> own head block as [64][40] (overwrites P; same-wave order OK)
    #pragma unroll
    for (int mt = 0; mt < 4; ++mt)
        #pragma unroll
        for (int nt = 0; nt < 2; ++nt)
            #pragma unroll
            for (int i = 0; i < 4; ++i)
                hq[(16*mt + 4*g + i) * 40 + 16*nt + c] = f2h_u(O[mt][nt][i]);

    __syncthreads();

    // ---- proj: wave w computes cols [32w, 32w+32) over all K=128 (4 source heads) ----
    f32x4 PO[4][2] = { { zf4, zf4 }, { zf4, zf4 }, { zf4, zf4 }, { zf4, zf4 } };
    #pragma unroll
    for (int ks = 0; ks < 4; ++ks) {
        const u16* ao = smem + ks * 4608;
        f16x8 afr[4];
        #pragma unroll
        for (int mt = 0; mt < 4; ++mt)
            afr[mt] = *(const f16x8*)(ao + (16*mt + c) * 40 + 8*g);          // 80-B rows: aligned
        #pragma unroll
        for (int lct = 0; lct < 2; ++lct) {
            f16x8 bfr = *(const f16x8*)(ws + (160 + (2*w + lct) * 4 + ks) * 512 + lane * 8);
            #pragma unroll
            for (int mt = 0; mt < 4; ++mt)
                PO[mt][lct] = MFMA_F16(afr[mt], bfr, PO[mt][lct]);
        }
    }
    __syncthreads();   // FIN overlaps attn-out regions other waves may still be reading

    // FIN f32 [64][132] overlays smem bytes [0, 33792)
    float* const fin = (float*)smem;
    #pragma unroll
    for (int lct = 0; lct < 2; ++lct) {
        float bv = bproj[32*w + 16*lct + c];
        #pragma unroll
        for (int mt = 0; mt < 4; ++mt)
            #pragma unroll
            for (int i = 0; i < 4; ++i)
                fin[(16*mt + 4*g + i) * 132 + 32*w + 16*lct + c] = PO[mt][lct][i] + bv;
    }
    __syncthreads();

    // ---- coalesced f32 store: 64 rows x 128 cols ----
    {
        const int row = tid >> 2, cb = (tid & 3) * 32;
        float* gout = out + (size_t)b * 8192 + row * 128 + cb;
        const float* src = fin + row * 132 + cb;
        #pragma unroll
        for (int q2 = 0; q2 < 8; ++q2)
            *(f32x4*)(gout + q2 * 4) = *(const f32x4*)(src + q2 * 4);
    }
}

extern "C" void kernel_launch(void* const* d_in, const int* in_sizes, int n_in,
                              void* d_out, int out_size, void* d_ws, size_t ws_size,
                              hipStream_t stream)
{
    const float* x     = (const float*)d_in[0];
    const float* f     = (const float*)d_in[1];
    const float* wq    = (const float*)d_in[2];
    const float* bq    = (const float*)d_in[3];
    const float* wkv   = (const float*)d_in[4];
    const float* bkv   = (const float*)d_in[5];
    const float* wq_f  = (const float*)d_in[6];
    const float* bq_f  = (const float*)d_in[7];
    const float* wkv_f = (const float*)d_in[8];
    const float* bkv_f = (const float*)d_in[9];
    const float* btab  = (const float*)d_in[10];
    const float* wproj = (const float*)d_in[11];
    const float* bproj = (const float*)d_in[12];
    u16* ws    = (u16*)d_ws;
    float* out = (float*)d_out;

    hipLaunchKernelGGL(wja_prep, dim3(192), dim3(64), 0, stream,
                       wq, wkv, wq_f, wkv_f, wproj, ws);
    hipLaunchKernelGGL(wja_fused, dim3(4096), dim3(256), 0, stream,
                       x, f, bq, bkv, bq_f, bkv_f, bproj, btab, ws, out);
}